// Round 6
// baseline (464.111 us; speedup 1.0000x reference)
//
#include <hip/hip_runtime.h>

typedef unsigned short u16;
typedef unsigned int u32;
typedef __attribute__((ext_vector_type(8))) short short8;
typedef __attribute__((ext_vector_type(4))) float f32x4;
typedef __attribute__((ext_vector_type(4))) u32 u32x4;
typedef __attribute__((ext_vector_type(2))) u32 u32x2;

#define NPT 128
#define DIM 512
#define KT 48
#define KC 32
#define BPB 16   // batches per block (persistent pipeline)

__device__ __forceinline__ u16 f2bf(float f) {
    unsigned u = __builtin_bit_cast(unsigned, f);
    return (u16)((u + 0x7FFFu + ((u >> 16) & 1u)) >> 16);
}

__device__ __forceinline__ u32 cvtpk(float lo, float hi) {
    u32 r;
    asm("v_cvt_pk_bf16_f32 %0, %1, %2" : "=v"(r) : "v"(lo), "v"(hi));
    return r;
}

// bank swizzle: 16B-granular XOR inside a 1KB row; distinct for rows n..n+7
// (phase-1 groups) AND for rows n, n+8, n+16, n+24 (phase-2 gather groups)
__device__ __forceinline__ int swz(int n) {
    return ((n & 7) ^ ((n >> 3) & 7)) << 4;
}

// Fold BN into clusters: cTs[k][d] = bf16(clusters[d][k] * s_k), t[k] = b_k - rm_k*s_k
__global__ void prep_kernel(const float* __restrict__ clusters,
                            const float* __restrict__ bn_w,
                            const float* __restrict__ bn_b,
                            const float* __restrict__ bn_rm,
                            const float* __restrict__ bn_rv,
                            u16* __restrict__ cTs,
                            float* __restrict__ tvec) {
    const int k = blockIdx.x;
    const float s = bn_w[k] * rsqrtf(bn_rv[k] + 1e-5f);
    if (threadIdx.x == 0) tvec[k] = bn_b[k] - bn_rm[k] * s;
    for (int d = threadIdx.x; d < DIM; d += blockDim.x)
        cTs[k * DIM + d] = f2bf(clusters[d * KT + k] * s);
}

// prefetch macros: issue 8 loads (4 rows) / convert landed group to bf16 stg
#define PREF_ISSUE(g)                                                        \
    do {                                                                     \
        _Pragma("unroll")                                                    \
        for (int rr = 0; rr < 4; ++rr) {                                     \
            int i = (g) * 4 + rr;                                            \
            t[2 * rr]     = *(const f32x4*)(nx + i * DIM + lane * 8);        \
            t[2 * rr + 1] = *(const f32x4*)(nx + i * DIM + lane * 8 + 4);    \
        }                                                                    \
    } while (0)

#define PREF_CONV(g)                                                         \
    do {                                                                     \
        _Pragma("unroll")                                                    \
        for (int rr = 0; rr < 4; ++rr) {                                     \
            int i = (g) * 4 + rr;                                            \
            u32x4 w;                                                         \
            w[0] = cvtpk(t[2 * rr][0],     t[2 * rr][1]);                    \
            w[1] = cvtpk(t[2 * rr][2],     t[2 * rr][3]);                    \
            w[2] = cvtpk(t[2 * rr + 1][0], t[2 * rr + 1][1]);                \
            w[3] = cvtpk(t[2 * rr + 1][2], t[2 * rr + 1][3]);                \
            stg[i] = w;                                                      \
        }                                                                    \
    } while (0)

__global__ __launch_bounds__(512)
void vlad_kernel(const float* __restrict__ x,
                 const float* __restrict__ c2,     // [512][32] fp32
                 const u16* __restrict__ cTs,      // [48][512] bf16
                 const float* __restrict__ tvec,   // [48]
                 float* __restrict__ out) {
    __shared__ __align__(16) u16 xs[NPT * DIM];    // 128 KB, swizzled row-major
    __shared__ __align__(16) u16 aT[KC][136];      // assignment^T
    __shared__ float asum_part[8][KC];
    __shared__ float colsq_part[8][KC];

    const int tid  = threadIdx.x;
    const int wave = tid >> 6;
    const int lane = tid & 63;
    const int lr   = lane & 15;
    const int lg   = lane >> 4;

    const int b0i = blockIdx.x * BPB;

    const float t0 = tvec[lr], t1 = tvec[16 + lr], t2 = tvec[32 + lr];

    // ---- prologue: stage batch b0i (wave-self: wave w rows [16w,16w+16)) ----
    {
        const float* gxw = x + (size_t)b0i * (NPT * DIM) + (wave * 16) * DIM;
        #pragma unroll
        for (int bt = 0; bt < 4; ++bt) {
            f32x4 tmp[8];
            #pragma unroll
            for (int i = 0; i < 8; ++i) {
                int it = bt * 8 + i;
                tmp[i] = *(const f32x4*)(gxw + (it >> 1) * DIM + (it & 1) * 256 + lane * 4);
            }
            #pragma unroll
            for (int i = 0; i < 8; ++i) {
                int it = bt * 8 + i;
                int r = wave * 16 + (it >> 1);
                u32x2 w2;
                w2[0] = cvtpk(tmp[i][0], tmp[i][1]);
                w2[1] = cvtpk(tmp[i][2], tmp[i][3]);
                int off = ((it & 1) * 512 + lane * 8) ^ swz(r);
                *(u32x2*)((char*)xs + r * 1024 + off) = w2;
            }
        }
    }

    for (int m = 0; m < BPB; ++m) {
        const int bm = b0i + m;
        const int pm = (m + 1 < BPB) ? bm + 1 : bm;   // clamp (last iter re-reads, harmless)
        const float* nx = x + (size_t)pm * (NPT * DIM) + (wave * 16) * DIM;
        f32x4 t[8];
        u32x4 stg[16];

        // ---- phase 1 (full unroll) + spread prefetch of batch m+1 ----
        f32x4 acc0 = {0.f,0.f,0.f,0.f}, acc1 = {0.f,0.f,0.f,0.f}, acc2 = {0.f,0.f,0.f,0.f};
        {
            const int nrow = wave * 16 + lr;
            const int rowbase = nrow * 1024;
            const int sw = swz(nrow);
            #pragma unroll
            for (int step = 0; step < 16; ++step) {
                if (step == 2)  { PREF_ISSUE(0); }
                if (step == 7)  { PREF_CONV(0); PREF_ISSUE(1); }
                if (step == 12) { PREF_CONV(1); PREF_ISSUE(2); }
                const int d0 = step * 32 + lg * 8;
                short8 af = *(const short8*)((const char*)xs + (rowbase + ((2 * d0) ^ sw)));
                short8 bb0 = *(const short8*)(cTs + (0 * 16 + lr) * DIM + d0);
                short8 bb1 = *(const short8*)(cTs + (1 * 16 + lr) * DIM + d0);
                short8 bb2 = *(const short8*)(cTs + (2 * 16 + lr) * DIM + d0);
                acc0 = __builtin_amdgcn_mfma_f32_16x16x32_bf16(af, bb0, acc0, 0, 0, 0);
                acc1 = __builtin_amdgcn_mfma_f32_16x16x32_bf16(af, bb1, acc1, 0, 0, 0);
                acc2 = __builtin_amdgcn_mfma_f32_16x16x32_bf16(af, bb2, acc2, 0, 0, 0);
            }
        }
        // ---- softmax over 48, keep 32; aT bf16; per-wave asum partials ----
        {
            float a0[4], a1[4];
            #pragma unroll
            for (int r = 0; r < 4; ++r) {
                float l0 = acc0[r] + t0, l1 = acc1[r] + t1, l2 = acc2[r] + t2;
                float mx = fmaxf(fmaxf(l0, l1), l2);
                #pragma unroll
                for (int o = 1; o < 16; o <<= 1) mx = fmaxf(mx, __shfl_xor(mx, o));
                float e0 = __expf(l0 - mx), e1 = __expf(l1 - mx), e2 = __expf(l2 - mx);
                float s = e0 + e1 + e2;
                #pragma unroll
                for (int o = 1; o < 16; o <<= 1) s += __shfl_xor(s, o);
                float inv = 1.0f / s;
                a0[r] = e0 * inv; a1[r] = e1 * inv;
            }
            float p0 = 0.f, p1 = 0.f;
            #pragma unroll
            for (int r = 0; r < 4; ++r) {
                int n = wave * 16 + lg * 4 + r;
                aT[lr][n]      = f2bf(a0[r]);
                aT[16 + lr][n] = f2bf(a1[r]);
                p0 += a0[r]; p1 += a1[r];
            }
            p0 += __shfl_xor(p0, 16); p0 += __shfl_xor(p0, 32);
            p1 += __shfl_xor(p1, 16); p1 += __shfl_xor(p1, 32);
            if (lane < 16) { asum_part[wave][lane] = p0; asum_part[wave][16 + lane] = p1; }
        }
        __syncthreads();   // b1: aT + asum_part ready

        // ---- phase 2 (+ tail of prefetch) ----
        f32x4 vacc[4][2];
        #pragma unroll
        for (int i = 0; i < 4; ++i) {
            vacc[i][0] = (f32x4){0.f,0.f,0.f,0.f};
            vacc[i][1] = (f32x4){0.f,0.f,0.f,0.f};
        }
        #pragma unroll
        for (int ns = 0; ns < 4; ++ns) {
            if (ns == 0) { PREF_CONV(2); PREF_ISSUE(3); }
            if (ns == 2) { PREF_CONV(3); }
            short8 bf0 = *(const short8*)(&aT[lr][ns * 32 + lg * 8]);
            short8 bf1 = *(const short8*)(&aT[16 + lr][ns * 32 + lg * 8]);
            const int n0 = ns * 32 + lg * 8;
            const int q  = (ns * 4 + lg) & 7;
            const char* pbase = (const char*)xs + n0 * 1024;
            #pragma unroll
            for (int dti = 0; dti < 4; ++dti) {
                const int d = (wave * 4 + dti) * 16 + lr;
                const int twod = 2 * d;
                short8 af;
                #pragma unroll
                for (int j = 0; j < 8; ++j)
                    af[j] = *(const short*)(pbase + j * 1024 + (twod ^ ((j ^ q) << 4)));
                vacc[dti][0] = __builtin_amdgcn_mfma_f32_16x16x32_bf16(af, bf0, vacc[dti][0], 0, 0, 0);
                vacc[dti][1] = __builtin_amdgcn_mfma_f32_16x16x32_bf16(af, bf1, vacc[dti][1], 0, 0, 0);
            }
        }
        __syncthreads();   // e: all phase-2 xs/aT reads complete

        // ---- write prefetched batch into xs (own rows; wave-self ordering) ----
        #pragma unroll
        for (int i = 0; i < 16; ++i) {
            int r = wave * 16 + i;
            *(u32x4*)((char*)xs + r * 1024 + ((lane * 16) ^ swz(r))) = stg[i];
        }

        // ---- epilogue ----
        float as0 = 0.f, as1 = 0.f;
        #pragma unroll
        for (int w2 = 0; w2 < 8; ++w2) {
            as0 += asum_part[w2][lr];
            as1 += asum_part[w2][16 + lr];
        }
        float cs0 = 0.f, cs1 = 0.f;
        #pragma unroll
        for (int dti = 0; dti < 4; ++dti) {
            #pragma unroll
            for (int r = 0; r < 4; ++r) {
                int d = (wave * 4 + dti) * 16 + lg * 4 + r;
                float v0 = vacc[dti][0][r] - as0 * c2[d * KC + lr];
                float v1 = vacc[dti][1][r] - as1 * c2[d * KC + 16 + lr];
                vacc[dti][0][r] = v0; vacc[dti][1][r] = v1;
                cs0 += v0 * v0; cs1 += v1 * v1;
            }
        }
        cs0 += __shfl_xor(cs0, 16); cs0 += __shfl_xor(cs0, 32);
        cs1 += __shfl_xor(cs1, 16); cs1 += __shfl_xor(cs1, 32);
        if (lane < 16) { colsq_part[wave][lane] = cs0; colsq_part[wave][16 + lane] = cs1; }
        __syncthreads();   // colsq-b
        float sq0 = 0.f, sq1 = 0.f;
        #pragma unroll
        for (int w2 = 0; w2 < 8; ++w2) {
            sq0 += colsq_part[w2][lr];
            sq1 += colsq_part[w2][16 + lr];
        }
        float cn0 = sqrtf(sq0), cn1 = sqrtf(sq1);
        float s10 = 1.0f / fmaxf(cn0, 1e-12f);
        float s11 = 1.0f / fmaxf(cn1, 1e-12f);
        float c10 = cn0 * s10, c11 = cn1 * s11;
        float tot = c10 * c10 + c11 * c11;
        #pragma unroll
        for (int o = 1; o < 16; o <<= 1) tot += __shfl_xor(tot, o);
        float gs = 1.0f / fmaxf(sqrtf(tot), 1e-12f);
        float sk0 = s10 * gs, sk1 = s11 * gs;
        {
            float* ob = out + (size_t)bm * (DIM * KC);
            #pragma unroll
            for (int dti = 0; dti < 4; ++dti) {
                #pragma unroll
                for (int r = 0; r < 4; ++r) {
                    int d = (wave * 4 + dti) * 16 + lg * 4 + r;
                    ob[d * KC + lr]      = vacc[dti][0][r] * sk0;
                    ob[d * KC + 16 + lr] = vacc[dti][1][r] * sk1;
                }
            }
        }
        // no barrier needed: next phase-1 reads only own xs rows (same-wave order);
        // cross-wave LDS writes in next iter are all behind b1(m+1)/colsq-b(m).
    }
}

extern "C" void kernel_launch(void* const* d_in, const int* in_sizes, int n_in,
                              void* d_out, int out_size, void* d_ws, size_t ws_size,
                              hipStream_t stream) {
    const float* x        = (const float*)d_in[0];
    const float* clusters = (const float*)d_in[1];
    const float* bn_w     = (const float*)d_in[2];
    const float* bn_b     = (const float*)d_in[3];
    const float* bn_rm    = (const float*)d_in[4];
    const float* bn_rv    = (const float*)d_in[5];
    const float* c2       = (const float*)d_in[6];
    float* out = (float*)d_out;

    u16*   cTs  = (u16*)d_ws;
    float* tvec = (float*)((char*)d_ws + KT * DIM * sizeof(u16));

    const int B = in_sizes[0] / (NPT * DIM);

    prep_kernel<<<KT, 256, 0, stream>>>(clusters, bn_w, bn_b, bn_rm, bn_rv, cTs, tvec);
    vlad_kernel<<<B / BPB, 512, 0, stream>>>(x, c2, cTs, tvec, out);
}